// Round 2
// baseline (153.264 us; speedup 1.0000x reference)
//
#include <hip/hip_runtime.h>

#define Bb 4
#define Qn 256
#define Kn 1024
#define Hn 128

// qp/kp are pre-scaled by 2*log2(e) so exp2(qp'+kp') = e^{2(qp+kp)}.
constexpr float SCALE = 2.88539008177792681f;  // 2*log2(e)
constexpr float LOG2E = 1.44269504088896341f;

#if __has_builtin(__builtin_amdgcn_exp2f)
#define EXP2F(x) __builtin_amdgcn_exp2f(x)
#else
#define EXP2F(x) exp2f(x)
#endif
#if __has_builtin(__builtin_amdgcn_rcpf)
#define RCPF(x) __builtin_amdgcn_rcpf(x)
#else
#define RCPF(x) (1.0f / (x))
#endif

// ---------------------------------------------------------------------------
// K1: q projection. qp[b,q,h] = SCALE * dot(query[b,q,:], Wq[h,:])
// Block = 128 threads (one per h), 4 rows per block staged in LDS.
// ---------------------------------------------------------------------------
__global__ __launch_bounds__(128) void proj_q_kernel(const float* __restrict__ x,
                                                     const float* __restrict__ W,
                                                     float* __restrict__ qp) {
    __shared__ float4 xs[128];  // 4 rows x 32 float4
    const int tid = threadIdx.x;
    const int r0 = blockIdx.x * 4;
    xs[tid] = ((const float4*)(x + (size_t)r0 * Hn))[tid];
    __syncthreads();
    const float4* W4 = (const float4*)W + (size_t)tid * (Hn / 4);
    float acc0 = 0.f, acc1 = 0.f, acc2 = 0.f, acc3 = 0.f;
#pragma unroll 8
    for (int d = 0; d < Hn / 4; ++d) {
        float4 w = W4[d];
        float4 a0 = xs[d];
        float4 a1 = xs[32 + d];
        float4 a2 = xs[64 + d];
        float4 a3 = xs[96 + d];
        acc0 = fmaf(w.x, a0.x, fmaf(w.y, a0.y, fmaf(w.z, a0.z, fmaf(w.w, a0.w, acc0))));
        acc1 = fmaf(w.x, a1.x, fmaf(w.y, a1.y, fmaf(w.z, a1.z, fmaf(w.w, a1.w, acc1))));
        acc2 = fmaf(w.x, a2.x, fmaf(w.y, a2.y, fmaf(w.z, a2.z, fmaf(w.w, a2.w, acc2))));
        acc3 = fmaf(w.x, a3.x, fmaf(w.y, a3.y, fmaf(w.z, a3.z, fmaf(w.w, a3.w, acc3))));
    }
    qp[(size_t)(r0 + 0) * Hn + tid] = acc0 * SCALE;
    qp[(size_t)(r0 + 1) * Hn + tid] = acc1 * SCALE;
    qp[(size_t)(r0 + 2) * Hn + tid] = acc2 * SCALE;
    qp[(size_t)(r0 + 3) * Hn + tid] = acc3 * SCALE;
}

// ---------------------------------------------------------------------------
// K2: k projection, stored transposed: kpT[b,h,k] (so score kernel reads
// contiguous k per h). 4 consecutive k per block -> one float4 store per h.
// ---------------------------------------------------------------------------
__global__ __launch_bounds__(128) void proj_k_kernel(const float* __restrict__ x,
                                                     const float* __restrict__ W,
                                                     float* __restrict__ kpT) {
    __shared__ float4 xs[128];
    const int tid = threadIdx.x;
    const int r0 = blockIdx.x * 4;
    xs[tid] = ((const float4*)(x + (size_t)r0 * Hn))[tid];
    __syncthreads();
    const float4* W4 = (const float4*)W + (size_t)tid * (Hn / 4);
    float acc0 = 0.f, acc1 = 0.f, acc2 = 0.f, acc3 = 0.f;
#pragma unroll 8
    for (int d = 0; d < Hn / 4; ++d) {
        float4 w = W4[d];
        float4 a0 = xs[d];
        float4 a1 = xs[32 + d];
        float4 a2 = xs[64 + d];
        float4 a3 = xs[96 + d];
        acc0 = fmaf(w.x, a0.x, fmaf(w.y, a0.y, fmaf(w.z, a0.z, fmaf(w.w, a0.w, acc0))));
        acc1 = fmaf(w.x, a1.x, fmaf(w.y, a1.y, fmaf(w.z, a1.z, fmaf(w.w, a1.w, acc1))));
        acc2 = fmaf(w.x, a2.x, fmaf(w.y, a2.y, fmaf(w.z, a2.z, fmaf(w.w, a2.w, acc2))));
        acc3 = fmaf(w.x, a3.x, fmaf(w.y, a3.y, fmaf(w.z, a3.z, fmaf(w.w, a3.w, acc3))));
    }
    const int b = r0 / Kn;
    const int k0 = r0 % Kn;
    float4 res = make_float4(acc0 * SCALE, acc1 * SCALE, acc2 * SCALE, acc3 * SCALE);
    ((float4*)kpT)[(size_t)(b * Hn + tid) * (Kn / 4) + (k0 >> 2)] = res;
}

// ---------------------------------------------------------------------------
// K3: score[b,q,k] = V - 2 * sum_h v[h] / (1 + 2^(qp'+kp'))   (== sum v tanh)
// Block: 256 thr, covers 4 q-rows x 512 k (khalf). Each thread: 4q x 2k accs.
// Per element: v_add, v_exp, v_add, v_rcp, v_fma  (~22 cy / 64 elems).
// ---------------------------------------------------------------------------
__global__ __launch_bounds__(256) void score_kernel(const float* __restrict__ qp,
                                                    const float* __restrict__ kpT,
                                                    const float* __restrict__ v,
                                                    float* __restrict__ scores) {
    const int tid = threadIdx.x;
    const int khalf = blockIdx.x;    // 0..1
    const int q0 = blockIdx.y * 4;   // 0..252
    const int b = blockIdx.z;

    __shared__ __align__(16) float qs[Hn][8];  // [h][0..3]=qp rows, [4]=v[h]
    const float* qpb = qp + ((size_t)b * Qn + q0) * Hn;
#pragma unroll
    for (int i = tid; i < 4 * Hn; i += 256) {
        qs[i & (Hn - 1)][i >> 7] = qpb[i];
    }
    if (tid < Hn) qs[tid][4] = v[tid];
    __syncthreads();

    // V = sum_h v[h]
    float V0 = 0.f, V1 = 0.f, V2 = 0.f, V3 = 0.f;
#pragma unroll 8
    for (int h = 0; h < Hn; h += 4) {
        V0 += qs[h][4]; V1 += qs[h + 1][4]; V2 += qs[h + 2][4]; V3 += qs[h + 3][4];
    }
    const float V = (V0 + V1) + (V2 + V3);

    const float2* kp2 = (const float2*)kpT + (size_t)b * Hn * (Kn / 2) + khalf * (Kn / 4) + tid;
    float a00 = 0.f, a01 = 0.f, a10 = 0.f, a11 = 0.f;
    float a20 = 0.f, a21 = 0.f, a30 = 0.f, a31 = 0.f;
#pragma unroll 4
    for (int h = 0; h < Hn; ++h) {
        float2 kv = kp2[h * (Kn / 2)];
        float vh = qs[h][4];
        float4 qv = *(const float4*)(&qs[h][0]);
        float e, r;
        e = EXP2F(qv.x + kv.x); r = RCPF(1.0f + e); a00 = fmaf(vh, r, a00);
        e = EXP2F(qv.x + kv.y); r = RCPF(1.0f + e); a01 = fmaf(vh, r, a01);
        e = EXP2F(qv.y + kv.x); r = RCPF(1.0f + e); a10 = fmaf(vh, r, a10);
        e = EXP2F(qv.y + kv.y); r = RCPF(1.0f + e); a11 = fmaf(vh, r, a11);
        e = EXP2F(qv.z + kv.x); r = RCPF(1.0f + e); a20 = fmaf(vh, r, a20);
        e = EXP2F(qv.z + kv.y); r = RCPF(1.0f + e); a21 = fmaf(vh, r, a21);
        e = EXP2F(qv.w + kv.x); r = RCPF(1.0f + e); a30 = fmaf(vh, r, a30);
        e = EXP2F(qv.w + kv.y); r = RCPF(1.0f + e); a31 = fmaf(vh, r, a31);
    }
    float2* s2 = (float2*)scores + (size_t)(b * Qn + q0) * (Kn / 2) + khalf * (Kn / 4) + tid;
    s2[0 * (Kn / 2)] = make_float2(V - 2.f * a00, V - 2.f * a01);
    s2[1 * (Kn / 2)] = make_float2(V - 2.f * a10, V - 2.f * a11);
    s2[2 * (Kn / 2)] = make_float2(V - 2.f * a20, V - 2.f * a21);
    s2[3 * (Kn / 2)] = make_float2(V - 2.f * a30, V - 2.f * a31);
}

// ---------------------------------------------------------------------------
// K4: in-place row softmax over K=1024. One block per (b,q).
// (mask term -1e-9*(1-mask) perturbs weights by ~1e-12 -> skipped)
// ---------------------------------------------------------------------------
__global__ __launch_bounds__(256) void softmax_kernel(float* __restrict__ attn) {
    const int row = blockIdx.x;
    const int tid = threadIdx.x;
    float4* rowp = (float4*)attn + (size_t)row * (Kn / 4);
    float4 sv = rowp[tid];

    __shared__ float redm[4], reds[4];
    const int lane = tid & 63, w = tid >> 6;

    float m = fmaxf(fmaxf(sv.x, sv.y), fmaxf(sv.z, sv.w));
#pragma unroll
    for (int off = 32; off; off >>= 1) m = fmaxf(m, __shfl_xor(m, off));
    if (lane == 0) redm[w] = m;
    __syncthreads();
    m = fmaxf(fmaxf(redm[0], redm[1]), fmaxf(redm[2], redm[3]));

    float4 e;
    e.x = EXP2F((sv.x - m) * LOG2E);
    e.y = EXP2F((sv.y - m) * LOG2E);
    e.z = EXP2F((sv.z - m) * LOG2E);
    e.w = EXP2F((sv.w - m) * LOG2E);
    float s = (e.x + e.y) + (e.z + e.w);
#pragma unroll
    for (int off = 32; off; off >>= 1) s += __shfl_xor(s, off);
    if (lane == 0) reds[w] = s;
    __syncthreads();
    s = (reds[0] + reds[1]) + (reds[2] + reds[3]);

    const float inv = RCPF(s);
    float4 o = make_float4(e.x * inv, e.y * inv, e.z * inv, e.w * inv);
    rowp[tid] = o;
}

// ---------------------------------------------------------------------------
// K5: context partials. ctx[b,q,h] = sum_k attn[b,q,k]*value[b,k,h].
// Split-k into 4 chunks of 256. Block=128 thr (h), 4 q rows per block.
// attn reads are wave-uniform (scalar-load friendly); value reads coalesced.
// ---------------------------------------------------------------------------
__global__ __launch_bounds__(128) void ctx_kernel(const float* __restrict__ attn,
                                                  const float* __restrict__ value,
                                                  float* __restrict__ pctx) {
    const int h = threadIdx.x;
    const int kc = blockIdx.x;  // 0..3
    const int qt = blockIdx.y;  // 0..63
    const int b = blockIdx.z;
    const float* vb = value + ((size_t)b * Kn + kc * (Kn / 4)) * Hn + h;
    const float* a0 = attn + ((size_t)b * Qn + qt * 4) * Kn + kc * (Kn / 4);
    float c0 = 0.f, c1 = 0.f, c2 = 0.f, c3 = 0.f;
#pragma unroll 4
    for (int k = 0; k < Kn / 4; ++k) {
        float val = vb[(size_t)k * Hn];
        c0 = fmaf(a0[k], val, c0);
        c1 = fmaf(a0[Kn + k], val, c1);
        c2 = fmaf(a0[2 * Kn + k], val, c2);
        c3 = fmaf(a0[3 * Kn + k], val, c3);
    }
    float* p = pctx + ((size_t)kc * (Bb * Qn) + b * Qn + qt * 4) * Hn + h;
    p[0] = c0;
    p[Hn] = c1;
    p[2 * Hn] = c2;
    p[3 * Hn] = c3;
}

__global__ __launch_bounds__(256) void reduce_ctx_kernel(const float* __restrict__ pctx,
                                                         float* __restrict__ ctx) {
    const int i = blockIdx.x * 256 + threadIdx.x;
    const int N = Bb * Qn * Hn;  // 131072
    ctx[i] = (pctx[i] + pctx[N + i]) + (pctx[2 * N + i] + pctx[3 * N + i]);
}

// ---------------------------------------------------------------------------
extern "C" void kernel_launch(void* const* d_in, const int* in_sizes, int n_in,
                              void* d_out, int out_size, void* d_ws, size_t ws_size,
                              hipStream_t stream) {
    const float* query = (const float*)d_in[0];  // (4,256,128)
    const float* key = (const float*)d_in[1];    // (4,1024,128)
    const float* value = (const float*)d_in[2];  // (4,1024,128)
    // d_in[3] = mask: unused (NEG_MASK_SCALE = -1e-9 -> effect ~1e-12 on weights)
    const float* Wq = (const float*)d_in[4];
    const float* Wk = (const float*)d_in[5];
    const float* v = (const float*)d_in[6];

    float* out = (float*)d_out;
    float* attn = out;                         // B*Q*K = 1048576 floats
    float* ctx = out + (size_t)Bb * Qn * Kn;   // B*Q*H = 131072 floats

    float* ws = (float*)d_ws;
    float* qp = ws;                            // 131072 floats (scaled)
    float* kpT = ws + 131072;                  // 524288 floats (scaled, transposed)
    float* pctx = ws + 131072 + 524288;        // 524288 floats (4 k-chunks)

    proj_q_kernel<<<dim3(Bb * Qn / 4), dim3(128), 0, stream>>>(query, Wq, qp);
    proj_k_kernel<<<dim3(Bb * Kn / 4), dim3(128), 0, stream>>>(key, Wk, kpT);
    // scores written into d_out's attn region (used as scratch), softmax in place
    score_kernel<<<dim3(2, Qn / 4, Bb), dim3(256), 0, stream>>>(qp, kpT, v, attn);
    softmax_kernel<<<dim3(Bb * Qn), dim3(256), 0, stream>>>(attn);
    ctx_kernel<<<dim3(4, Qn / 4, Bb), dim3(128), 0, stream>>>(attn, value, pctx);
    reduce_ctx_kernel<<<dim3(Bb * Qn * Hn / 256), dim3(256), 0, stream>>>(pctx, ctx);
}